// Round 5
// baseline (9343.468 us; speedup 1.0000x reference)
//
#include <hip/hip_runtime.h>
#include <math.h>

// Problem constants (fixed by reference)
#define T   1024
#define NB  16
#define HD  512

// ws layout (float offsets)
#define OFF_BAR  0                         // 256 ints: flag[2][128] step counters
#define OFF_HH   256                       // h_hist [2][T][NB][HD] = 16,777,216 floats
#define OFF_SH   (OFF_HH + 16777216)       // SH [16384][512] = 8,388,608 floats
#define OFF_SEGP (OFF_SH + 8388608)        // [16384]
#define OFF_GCTX (OFF_SEGP + 16384)        // [16][1024]
#define OFF_SEL  (OFF_GCTX + 16384)        // ints [16][12]

typedef unsigned long long u64;

__device__ __forceinline__ float sigmoidf_(float x){ return 1.0f/(1.0f + __expf(-x)); }
// fast tanh via exp2-based __expf; |err| ~1e-7, graceful saturation at +/-1
__device__ __forceinline__ float tanhf_(float x){ return 1.0f - 2.0f/(1.0f + __expf(2.0f*x)); }

// ---------------------------------------------------------------------------
// Persistent bidirectional LSTM. grid=256 wgs (1 per CU), block=512 (8 waves).
// wg -> (dir = wg&1, slice = wg>>1 of 4 hidden units). Weights in VGPRs.
// Wave wid = (bg = wid>>1 : 4 batches, ug = wid&1 : 2 units).
// Per-wave rows: rgl = gate*2+ui (8 rows = 4 gates x 2 units) -> all 4 gates of
// a (batch,unit) live INSIDE the wave -> gate exchange = 3 shfl_xor, no LDS,
// and NO __syncthreads anywhere in the step loop.
//
// Sync (per step):
//   producer (each wave): sc1 h-stores -> vmcnt(0) -> lane0 LDS cnt[s&1]++;
//     8th wave resets cnt and writes per-wg flag[dir][slice]=s+1 (sc1).
//   consumer: wave0 polls the 128 flags (relaxed-AGENT loads, no L2 inv),
//     then releases sibling waves via an LDS word; h read = plain cached
//     float4 loads (fresh address per step; L2-shared within the XCD).
// x-gather is issued before the wait (hides under poll); h-loads are issued
// in two batch-pairs interleaved with FMA bursts (hides LLC latency).
// ---------------------------------------------------------------------------
__global__ __launch_bounds__(512, 1)
void lstm_kernel(const int* __restrict__ instr, const float* __restrict__ emb,
                 const float* __restrict__ wih_f, const float* __restrict__ whh_f,
                 const float* __restrict__ bih_f, const float* __restrict__ bhh_f,
                 const float* __restrict__ wih_b, const float* __restrict__ whh_b,
                 const float* __restrict__ bih_b, const float* __restrict__ bhh_b,
                 float* __restrict__ ws)
{
    float* h_hist = ws + OFF_HH;
    int* flags = (int*)ws;            // flag[2][128]

    const int wg    = blockIdx.x;     // 0..255
    const int dir   = wg & 1;
    const int slice = wg >> 1;        // 0..127
    const int U     = slice * 4;      // hidden-unit base

    int* barf = flags + dir*128;

    const float* wih = dir ? wih_b : wih_f;
    const float* whh = dir ? whh_b : whh_f;
    const float* bih = dir ? bih_b : bih_f;
    const float* bhh = dir ? bhh_b : bhh_f;

    const int tid  = threadIdx.x;
    const int wid  = tid >> 6;        // 0..7
    const int lane = tid & 63;        // k-chunk id (8 k's per lane)
    const int bg   = wid >> 1;        // 0..3 : batches bg*4..bg*4+3
    const int ug   = wid & 1;         // 0..1 : units U+ug*2, U+ug*2+1

    __shared__ int cnt[2];            // per-step-parity producer counters
    __shared__ int release;           // consumer release word
    if (tid == 0){ cnt[0] = 0; cnt[1] = 0; release = 0; }
    __syncthreads();                  // prologue only

    // Weight slices: local row rgl = gate*2 + ui, k = lane*8..+8
    float wi[64], wh[64];
#pragma unroll
    for (int ri = 0; ri < 8; ++ri){
        int gate = ri >> 1, ui = ri & 1;
        size_t row = (size_t)(gate*HD + U + ug*2 + ui) * HD + lane*8;
        float4 a0 = *(const float4*)(wih + row);
        float4 a1 = *(const float4*)(wih + row + 4);
        float4 b0 = *(const float4*)(whh + row);
        float4 b1 = *(const float4*)(whh + row + 4);
        wi[ri*8+0]=a0.x; wi[ri*8+1]=a0.y; wi[ri*8+2]=a0.z; wi[ri*8+3]=a0.w;
        wi[ri*8+4]=a1.x; wi[ri*8+5]=a1.y; wi[ri*8+6]=a1.z; wi[ri*8+7]=a1.w;
        wh[ri*8+0]=b0.x; wh[ri*8+1]=b0.y; wh[ri*8+2]=b0.z; wh[ri*8+3]=b0.w;
        wh[ri*8+4]=b1.x; wh[ri*8+5]=b1.y; wh[ri*8+6]=b1.z; wh[ri*8+7]=b1.w;
    }

    // Reduce-scatter ownership: lane ends holding flat j5 = bitrev5(lane&31),
    // j5 = bi*8 + gate*2 + ui  ->  bi=j5>>3, gate=(j5>>1)&3, ui=j5&1.
    const int j5 = ((lane&1)<<4)|((lane&2)<<2)|(lane&4)|((lane&8)>>2)|((lane&16)>>4);
    const int own_bi = j5 >> 3;
    const int own_ui = j5 & 1;
    const bool owner = (lane < 32) && ((lane & 12) == 0);   // gate==0 holders, low half
    const int own_b  = bg*4 + own_bi;
    const int own_u  = U + ug*2 + own_ui;

    const float bI = bih[0*HD + own_u] + bhh[0*HD + own_u];
    const float bF = bih[1*HD + own_u] + bhh[1*HD + own_u];
    const float bG = bih[2*HD + own_u] + bhh[2*HD + own_u];
    const float bO = bih[3*HD + own_u] + bhh[3*HD + own_u];
    float cst = 0.0f;

    for (int s = 0; s < T; ++s){
        const int tp = dir ? (T-1-s) : s;   // original-time index

        // ---- issue x-gather early: it flies during the poll below
        float4 xb[8];
#pragma unroll
        for (int bi = 0; bi < 4; ++bi){
            int b = bg*4 + bi;
            int idx = instr[b*T + tp];
            const float* px = emb + (size_t)idx*HD + lane*8;
            xb[bi*2]   = *(const float4*)px;
            xb[bi*2+1] = *(const float4*)(px + 4);
        }

        // ---- wait for step s-1 of all 128 wgs in this direction
        if (s > 0){
            if (wid == 0){
                for (;;){
                    int v0 = __hip_atomic_load(barf + lane,      __ATOMIC_RELAXED, __HIP_MEMORY_SCOPE_AGENT);
                    int v1 = __hip_atomic_load(barf + 64 + lane, __ATOMIC_RELAXED, __HIP_MEMORY_SCOPE_AGENT);
                    if (__all((v0 >= s) && (v1 >= s))) break;
                    __builtin_amdgcn_s_sleep(1);
                }
                if (lane == 0)
                    __hip_atomic_store(&release, s, __ATOMIC_RELAXED, __HIP_MEMORY_SCOPE_WORKGROUP);
            }
            while (__hip_atomic_load(&release, __ATOMIC_RELAXED, __HIP_MEMORY_SCOPE_WORKGROUP) < s) {}
        }

        float a[32];
#pragma unroll
        for (int j = 0; j < 32; ++j) a[j] = 0.0f;

        if (s > 0){
            const int tprev = dir ? (tp + 1) : (tp - 1);
            const float* hbase = h_hist + (size_t)(dir*T + tprev)*NB*HD;

            // pair 0: issue h-loads for batches 0,1
            const float* p0 = hbase + (size_t)(bg*4 + 0)*HD + lane*8;
            const float* p1 = hbase + (size_t)(bg*4 + 1)*HD + lane*8;
            float4 h00 = *(const float4*)p0, h01 = *(const float4*)(p0+4);
            float4 h10 = *(const float4*)p1, h11 = *(const float4*)(p1+4);

            // x-proj batches 0,1 while pair-0 h flies
#pragma unroll
            for (int bi = 0; bi < 2; ++bi){
                float xs[8] = {xb[bi*2].x,xb[bi*2].y,xb[bi*2].z,xb[bi*2].w,
                               xb[bi*2+1].x,xb[bi*2+1].y,xb[bi*2+1].z,xb[bi*2+1].w};
#pragma unroll
                for (int kk = 0; kk < 8; ++kk)
#pragma unroll
                    for (int ri = 0; ri < 8; ++ri)
                        a[bi*8+ri] = fmaf(xs[kk], wi[ri*8+kk], a[bi*8+ri]);
            }

            // pair 1: issue h-loads for batches 2,3
            const float* p2 = hbase + (size_t)(bg*4 + 2)*HD + lane*8;
            const float* p3 = hbase + (size_t)(bg*4 + 3)*HD + lane*8;
            float4 h20 = *(const float4*)p2, h21 = *(const float4*)(p2+4);
            float4 h30 = *(const float4*)p3, h31 = *(const float4*)(p3+4);

            // h-proj batches 0,1
            {
                float hs0[8] = {h00.x,h00.y,h00.z,h00.w,h01.x,h01.y,h01.z,h01.w};
                float hs1[8] = {h10.x,h10.y,h10.z,h10.w,h11.x,h11.y,h11.z,h11.w};
#pragma unroll
                for (int kk = 0; kk < 8; ++kk){
#pragma unroll
                    for (int ri = 0; ri < 8; ++ri){
                        a[0*8+ri] = fmaf(hs0[kk], wh[ri*8+kk], a[0*8+ri]);
                        a[1*8+ri] = fmaf(hs1[kk], wh[ri*8+kk], a[1*8+ri]);
                    }
                }
            }

            // x-proj batches 2,3 while pair-1 h flies
#pragma unroll
            for (int bi = 2; bi < 4; ++bi){
                float xs[8] = {xb[bi*2].x,xb[bi*2].y,xb[bi*2].z,xb[bi*2].w,
                               xb[bi*2+1].x,xb[bi*2+1].y,xb[bi*2+1].z,xb[bi*2+1].w};
#pragma unroll
                for (int kk = 0; kk < 8; ++kk)
#pragma unroll
                    for (int ri = 0; ri < 8; ++ri)
                        a[bi*8+ri] = fmaf(xs[kk], wi[ri*8+kk], a[bi*8+ri]);
            }

            // h-proj batches 2,3
            {
                float hs2[8] = {h20.x,h20.y,h20.z,h20.w,h21.x,h21.y,h21.z,h21.w};
                float hs3[8] = {h30.x,h30.y,h30.z,h30.w,h31.x,h31.y,h31.z,h31.w};
#pragma unroll
                for (int kk = 0; kk < 8; ++kk){
#pragma unroll
                    for (int ri = 0; ri < 8; ++ri){
                        a[2*8+ri] = fmaf(hs2[kk], wh[ri*8+kk], a[2*8+ri]);
                        a[3*8+ri] = fmaf(hs3[kk], wh[ri*8+kk], a[3*8+ri]);
                    }
                }
            }
        } else {
            // s==0: x-proj only (h0 = 0)
#pragma unroll
            for (int bi = 0; bi < 4; ++bi){
                float xs[8] = {xb[bi*2].x,xb[bi*2].y,xb[bi*2].z,xb[bi*2].w,
                               xb[bi*2+1].x,xb[bi*2+1].y,xb[bi*2+1].z,xb[bi*2+1].w};
#pragma unroll
                for (int kk = 0; kk < 8; ++kk)
#pragma unroll
                    for (int ri = 0; ri < 8; ++ri)
                        a[bi*8+ri] = fmaf(xs[kk], wi[ri*8+kk], a[bi*8+ri]);
            }
        }

        // ---- reduce-scatter: 32 values over 64 lanes (5 stages + k-half merge)
#pragma unroll
        for (int m = 0; m < 5; ++m){
            const int half = 16 >> m;
            const bool up = (lane >> m) & 1;
#pragma unroll
            for (int jj = 0; jj < 16; ++jj){
                if (jj < half){
                    float lo = a[jj], hi = a[jj+half];
                    float rlo = __shfl_xor(lo, 1<<m, 64);
                    float rhi = __shfl_xor(hi, 1<<m, 64);
                    a[jj] = up ? (hi + rhi) : (lo + rlo);
                }
            }
        }
        a[0] += __shfl_xor(a[0], 32, 64);

        // ---- gate gather inside the wave: i@L, f@L^8, g@L^4, o@L^12
        float vi = a[0];
        float vf = __shfl_xor(vi, 8, 64);
        float vg = __shfl_xor(vi, 4, 64);
        float vo = __shfl_xor(vi, 12, 64);

        float iv = sigmoidf_(vi + bI);
        float fv = sigmoidf_(vf + bF);
        float gv = tanhf_  (vg + bG);
        float ov = sigmoidf_(vo + bO);
        cst = fv*cst + iv*gv;                 // garbage on non-owner lanes (unused)
        float hv = ov * tanhf_(cst);

        if (owner)
            __hip_atomic_store(&h_hist[((size_t)(dir*T + tp)*NB + own_b)*HD + own_u], hv,
                               __ATOMIC_RELAXED, __HIP_MEMORY_SCOPE_AGENT);

        // producer tail: ack h-stores at LLC, then count in via LDS; 8th wave
        // resets the counter and publishes the per-wg flag.
        asm volatile("s_waitcnt vmcnt(0)" ::: "memory");
        __builtin_amdgcn_sched_barrier(0);
        if (lane == 0){
            int prev = atomicAdd(&cnt[s & 1], 1);
            if (prev == 7){
                cnt[s & 1] = 0;               // safe: reused only at step s+2
                __hip_atomic_store(barf + slice, s + 1, __ATOMIC_RELAXED, __HIP_MEMORY_SCOPE_AGENT);
            }
        }
    }
}

// ---------------------------------------------------------------------------
// SH = relu(enc @ ws1.T + bs1)   M=16384 N=512 K=1024, fp32 64x64x16 tiles
// ---------------------------------------------------------------------------
__global__ __launch_bounds__(256, 2)
void seg_gemm(const float* __restrict__ ws_, const float* __restrict__ ws1,
              const float* __restrict__ bs1)
{
    const float* h_hist = ws_ + OFF_HH;
    float* SH = (float*)(ws_ + OFF_SH);
    __shared__ float As[64][17];
    __shared__ float Bs[64][17];
    const int m0 = blockIdx.x * 64;
    const int n0 = blockIdx.y * 64;
    const int tid = threadIdx.x;
    const int r  = tid >> 2;
    const int kq = (tid & 3) * 4;
    const int ty = tid >> 4, tx = tid & 15;
    const int bI = m0 >> 10;          // tile stays inside one batch
    const int t0 = m0 & 1023;

    float acc[4][4];
#pragma unroll
    for (int i=0;i<4;i++)
#pragma unroll
        for (int j=0;j<4;j++) acc[i][j]=0.0f;

    for (int kb = 0; kb < 1024; kb += 16){
        int kk = kb + kq;
        const float* ap = (kk < 512)
            ? h_hist + ((size_t)(t0 + r)*NB + bI)*HD + kk
            : h_hist + ((size_t)(T + t0 + r)*NB + bI)*HD + (kk - 512);
        float4 av = *(const float4*)ap;
        As[r][kq+0]=av.x; As[r][kq+1]=av.y; As[r][kq+2]=av.z; As[r][kq+3]=av.w;
        float4 bv = *(const float4*)(ws1 + (size_t)(n0 + r)*1024 + kk);
        Bs[r][kq+0]=bv.x; Bs[r][kq+1]=bv.y; Bs[r][kq+2]=bv.z; Bs[r][kq+3]=bv.w;
        __syncthreads();
#pragma unroll
        for (int k2 = 0; k2 < 16; ++k2){
            float av_[4], bv_[4];
#pragma unroll
            for (int i=0;i<4;i++) av_[i] = As[ty*4+i][k2];
#pragma unroll
            for (int j=0;j<4;j++) bv_[j] = Bs[tx*4+j][k2];
#pragma unroll
            for (int i=0;i<4;i++)
#pragma unroll
                for (int j=0;j<4;j++) acc[i][j] = fmaf(av_[i], bv_[j], acc[i][j]);
        }
        __syncthreads();
    }
#pragma unroll
    for (int i=0;i<4;i++){
        int m = m0 + ty*4 + i;
#pragma unroll
        for (int j=0;j<4;j++){
            int n = n0 + tx*4 + j;
            SH[(size_t)m*512 + n] = fmaxf(acc[i][j] + bs1[n], 0.0f);
        }
    }
}

// ---------------------------------------------------------------------------
// scores -> sigmoid -> seg_probs (ws copy + d_out)
// ---------------------------------------------------------------------------
__global__ void seg_score(const float* __restrict__ ws_, const float* __restrict__ ws2,
                          const float* __restrict__ bs2, float* __restrict__ dout)
{
    const float* SH = ws_ + OFF_SH;
    float* segp = (float*)(ws_ + OFF_SEGP);
    int row  = blockIdx.x*4 + (threadIdx.x >> 6);
    int lane = threadIdx.x & 63;
    const float* p = SH + (size_t)row*512 + lane*8;
    const float* q = ws2 + lane*8;
    float4 a0=*(const float4*)p, a1=*(const float4*)(p+4);
    float4 b0=*(const float4*)q, b1=*(const float4*)(q+4);
    float ssum = a0.x*b0.x + a0.y*b0.y + a0.z*b0.z + a0.w*b0.w
               + a1.x*b1.x + a1.y*b1.y + a1.z*b1.z + a1.w*b1.w;
#pragma unroll
    for (int m=1;m<64;m<<=1) ssum += __shfl_xor(ssum, m, 64);
    if (lane == 0){
        float z = ssum + bs2[0];
        float pr = 1.0f/(1.0f + __expf(-z));
        segp[row] = pr;
        dout[81920 + row] = pr;
    }
}

// ---------------------------------------------------------------------------
// Per-batch: mask scan (count, first-10 idx), pooled -> gctx
// ---------------------------------------------------------------------------
__global__ void select_gctx(float* __restrict__ ws_, const float* __restrict__ wgm,
                            const float* __restrict__ bgv)
{
    const float* h_hist = ws_ + OFF_HH;
    const float* segp   = ws_ + OFF_SEGP;
    float* gctx = ws_ + OFF_GCTX;
    int* sel = (int*)(ws_ + OFF_SEL);
    int b = blockIdx.x, tid = threadIdx.x;
    __shared__ unsigned char flag[1024];
    __shared__ float pool[1024];
    for (int j = tid; j < 1024; j += 256){
        flag[j] = segp[b*1024 + j] > 0.5f ? 1 : 0;
        pool[j] = (j < 512) ? h_hist[((size_t)1023*NB + b)*HD + j]
                            : h_hist[((size_t)T*NB + b)*HD + (j - 512)];
    }
    __syncthreads();
    if (tid == 0){
        int c = 0;
        int tmp[10];
        for (int j = 0; j < 10; ++j) tmp[j] = 0;
        for (int t = 0; t < 1024; ++t){
            if (flag[t]){ if (c < 10) tmp[c] = t; c++; }
        }
        for (int j = 0; j < 10; ++j) sel[b*12 + j] = tmp[j];
        sel[b*12 + 10] = c;
        sel[b*12 + 11] = 0;
    }
    __syncthreads();
    for (int n = tid; n < 1024; n += 256){
        float acc = bgv[n];
        const float* wr = wgm + (size_t)n*1024;
        for (int k = 0; k < 1024; k += 4){
            acc += wr[k]*pool[k] + wr[k+1]*pool[k+1] + wr[k+2]*pool[k+2] + wr[k+3]*pool[k+3];
        }
        gctx[b*1024 + n] = acc;
    }
}

// ---------------------------------------------------------------------------
// Decoder: one block per (b,slot)
// ---------------------------------------------------------------------------
__global__ void decode(const float* __restrict__ ws_, const float* __restrict__ wd1,
                       const float* __restrict__ bd1, const float* __restrict__ wd2,
                       const float* __restrict__ bd2, float* __restrict__ dout)
{
    const float* h_hist = ws_ + OFF_HH;
    const float* gctx   = ws_ + OFF_GCTX;
    const int* sel = (const int*)(ws_ + OFF_SEL);
    int blk = blockIdx.x;
    int b = blk / 10, slot = blk % 10;
    int tid = threadIdx.x;
    int count = sel[b*12 + 10];
    int nval = count < 10 ? count : 10;
    bool empty = (count == 0);
    float* outp = dout + (size_t)(b*10 + slot)*512;
    if (slot >= nval && !(empty && slot == 0)){
        for (int n = tid; n < 512; n += 256) outp[n] = 0.0f;
        return;
    }
    __shared__ float row[1024];
    __shared__ float dh[512];
    if (empty){
        for (int j = tid; j < 1024; j += 256) row[j] = gctx[b*1024 + j];
    } else {
        int t = sel[b*12 + slot];
        for (int j = tid; j < 1024; j += 256)
            row[j] = (j < 512) ? h_hist[((size_t)t*NB + b)*HD + j]
                               : h_hist[((size_t)(T + t)*NB + b)*HD + (j-512)];
    }
    __syncthreads();
    for (int d = tid; d < 512; d += 256){
        float acc = bd1[d];
        const float* wr = wd1 + (size_t)d*1024;
        for (int k = 0; k < 1024; ++k) acc += wr[k]*row[k];
        dh[d] = fmaxf(acc, 0.0f);
    }
    __syncthreads();
    for (int n = tid; n < 512; n += 256){
        float acc = bd2[n];
        const float* wr = wd2 + (size_t)n*512;
        for (int k = 0; k < 512; ++k) acc += wr[k]*dh[k];
        outp[n] = acc;
    }
}

extern "C" void kernel_launch(void* const* d_in, const int* in_sizes, int n_in,
                              void* d_out, int out_size, void* d_ws, size_t ws_size,
                              hipStream_t stream)
{
    const int*   instr = (const int*)d_in[0];
    const float* emb   = (const float*)d_in[1];
    const float* wih_f = (const float*)d_in[2];
    const float* whh_f = (const float*)d_in[3];
    const float* bih_f = (const float*)d_in[4];
    const float* bhh_f = (const float*)d_in[5];
    const float* wih_b = (const float*)d_in[6];
    const float* whh_b = (const float*)d_in[7];
    const float* bih_b = (const float*)d_in[8];
    const float* bhh_b = (const float*)d_in[9];
    const float* wg_   = (const float*)d_in[10];
    const float* bg_   = (const float*)d_in[11];
    const float* ws1   = (const float*)d_in[12];
    const float* bs1   = (const float*)d_in[13];
    const float* ws2   = (const float*)d_in[14];
    const float* bs2   = (const float*)d_in[15];
    const float* wd1   = (const float*)d_in[16];
    const float* bd1   = (const float*)d_in[17];
    const float* wd2   = (const float*)d_in[18];
    const float* bd2   = (const float*)d_in[19];
    float* out = (float*)d_out;
    float* ws  = (float*)d_ws;

    // zero the per-wg step flags (captured as a memset node; re-runs every replay)
    hipMemsetAsync(d_ws, 0, 1024, stream);

    hipLaunchKernelGGL(lstm_kernel, dim3(256), dim3(512), 0, stream,
                       instr, emb, wih_f, whh_f, bih_f, bhh_f,
                       wih_b, whh_b, bih_b, bhh_b, ws);
    hipLaunchKernelGGL(seg_gemm, dim3(256, 8), dim3(256), 0, stream, ws, ws1, bs1);
    hipLaunchKernelGGL(seg_score, dim3(4096), dim3(256), 0, stream, ws, ws2, bs2, out);
    hipLaunchKernelGGL(select_gctx, dim3(16), dim3(256), 0, stream, ws, wg_, bg_);
    hipLaunchKernelGGL(decode, dim3(160), dim3(256), 0, stream, ws, wd1, bd1, wd2, bd2, out);
}

// Round 6
// 5649.466 us; speedup vs baseline: 1.6539x; 1.6539x over previous
//
#include <hip/hip_runtime.h>
#include <math.h>

// Problem constants (fixed by reference)
#define T   1024
#define NB  16
#define HD  512

// ws layout (float offsets)
#define OFF_BAR  0                         // 256 ints: flag[2][128] step counters
#define OFF_HX   256                       // HX [2][T][128 slices][64] = 16,777,216 floats
#define OFF_SH   (OFF_HX + 16777216)       // SH [16384][512] = 8,388,608 floats
#define OFF_SEGP (OFF_SH + 8388608)        // [16384]
#define OFF_GCTX (OFF_SEGP + 16384)        // [16][1024]
#define OFF_SEL  (OFF_GCTX + 16384)        // ints [16][12]

typedef unsigned long long u64;

__device__ __forceinline__ float sigmoidf_(float x){ return 1.0f/(1.0f + __expf(-x)); }
// fast tanh via exp2-based __expf; |err| ~1e-7, graceful saturation at +/-1
__device__ __forceinline__ float tanhf_(float x){ return 1.0f - 2.0f/(1.0f + __expf(2.0f*x)); }

// enc element (dirIdx, t, b, k) in the compact exchange layout:
// HX[((dirIdx*T + t)*128 + (k>>2))*64 + b*4 + (k&3)]
__device__ __forceinline__ size_t hx_idx(int dirIdx, int t, int b, int k){
    return ((size_t)(dirIdx*T + t)*128 + (k>>2))*64 + b*4 + (k&3);
}

// ---------------------------------------------------------------------------
// Persistent bidirectional LSTM. grid=256 wgs (1 per CU), block=512 (8 waves).
// wg -> (dir = wg&1, slice = wg>>1 of 4 hidden units). Weights in VGPRs.
// wave wid: bg=wid>>1 (4 batches), rg=wid&1 (8 gate-rows). Per thread a[32].
// Structure = round 4 (proven): 2 block barriers/step, LDS gbuf gate exchange,
// wave0 computes gates. Round 5's software-spin replacement REGRESSED 2x:
// s_barrier waits are ~free, software LDS spinning isn't.
//
// NEW: compact h-exchange layout HX[dir][t][slice][b*4+u] (same 64MB, permuted):
//   producer wave0: 64 lanes store 64 CONTIGUOUS floats (256B = 4 lines) per wg
//     -> one coalesced sc1 burst; vmcnt(0) acks a single burst; write-through
//     traffic halves vs 16 scattered 16B chunks.
//   consumer: lane L reads exactly two full 64B lines (slices 2L, 2L+1 at its
//     batch-group offset) -> every fetched line fully consumed. Addresses are
//     fresh per step (never cached earlier), so plain cached loads stay safe.
// ---------------------------------------------------------------------------
__global__ __launch_bounds__(512, 1)
void lstm_kernel(const int* __restrict__ instr, const float* __restrict__ emb,
                 const float* __restrict__ wih_f, const float* __restrict__ whh_f,
                 const float* __restrict__ bih_f, const float* __restrict__ bhh_f,
                 const float* __restrict__ wih_b, const float* __restrict__ whh_b,
                 const float* __restrict__ bih_b, const float* __restrict__ bhh_b,
                 float* __restrict__ ws)
{
    float* HX = ws + OFF_HX;
    int* flags = (int*)ws;            // flag[2][128]

    const int wg    = blockIdx.x;     // 0..255
    const int dir   = wg & 1;
    const int slice = wg >> 1;        // 0..127
    const int U     = slice * 4;      // hidden-unit base

    int* barf = flags + dir*128;

    const float* wih = dir ? wih_b : wih_f;
    const float* whh = dir ? whh_b : whh_f;
    const float* bih = dir ? bih_b : bih_f;
    const float* bhh = dir ? bhh_b : bhh_f;

    const int tid  = threadIdx.x;
    const int wid  = tid >> 6;        // 0..7
    const int lane = tid & 63;        // k-chunk id (8 k's per lane)
    const int bg   = wid >> 1;        // 0..3 : batches bg*4..bg*4+3
    const int rg   = wid & 1;         // 0..1 : local gate-rows rg*8..rg*8+7

    // Load weight slices into registers: local row (rg*8+ri), k = lane*8..+8
    float wi[64], wh[64];
#pragma unroll
    for (int ri = 0; ri < 8; ++ri){
        int rgl = rg*8 + ri;
        int gate = rgl >> 2, unit = rgl & 3;
        size_t row = (size_t)(gate*HD + U + unit) * HD + lane*8;
        float4 a0 = *(const float4*)(wih + row);
        float4 a1 = *(const float4*)(wih + row + 4);
        float4 b0 = *(const float4*)(whh + row);
        float4 b1 = *(const float4*)(whh + row + 4);
        wi[ri*8+0]=a0.x; wi[ri*8+1]=a0.y; wi[ri*8+2]=a0.z; wi[ri*8+3]=a0.w;
        wi[ri*8+4]=a1.x; wi[ri*8+5]=a1.y; wi[ri*8+6]=a1.z; wi[ri*8+7]=a1.w;
        wh[ri*8+0]=b0.x; wh[ri*8+1]=b0.y; wh[ri*8+2]=b0.z; wh[ri*8+3]=b0.w;
        wh[ri*8+4]=b1.x; wh[ri*8+5]=b1.y; wh[ri*8+6]=b1.z; wh[ri*8+7]=b1.w;
    }

    // Biases for owner lanes (tid<64 owns (b=tid>>2, u=tid&3))
    float bI, bF, bG, bO, cst = 0.0f;
    {
        int u = tid & 3;
        bI = bih[0*HD + U + u] + bhh[0*HD + U + u];
        bF = bih[1*HD + U + u] + bhh[1*HD + U + u];
        bG = bih[2*HD + U + u] + bhh[2*HD + U + u];
        bO = bih[3*HD + U + u] + bhh[3*HD + U + u];
    }

    __shared__ float gbuf[256];

    // reduce-scatter ownership (32 values, 5 xor stages + cross-half merge):
    // j = bit0*16 + bit1*8 + bit2*4 + bit3*2 + bit4*1  (bitrev5 of lane&31)
    const int jown = ((lane&1)<<4)|((lane&2)<<2)|(lane&4)|((lane&8)>>2)|((lane&16)>>4);
    const int own_bi  = jown >> 3;            // 0..3
    const int own_rgl = rg*8 + (jown & 7);    // 0..15
    const int gslot   = (own_rgl >> 2)*64 + (bg*4 + own_bi)*4 + (own_rgl & 3);

    for (int s = 0; s < T; ++s){
        const int tp = dir ? (T-1-s) : s;   // original-time index for input AND h store

        // ---- x gather + x-projection: independent of the barrier, hides latency
        float a[32];
#pragma unroll
        for (int j = 0; j < 32; ++j) a[j] = 0.0f;

#pragma unroll
        for (int bi = 0; bi < 4; ++bi){
            int b = bg*4 + bi;
            int idx = instr[b*T + tp];
            const float* px = emb + (size_t)idx*HD + lane*8;
            float4 x0 = *(const float4*)px;
            float4 x1 = *(const float4*)(px + 4);
            float xs[8] = {x0.x,x0.y,x0.z,x0.w,x1.x,x1.y,x1.z,x1.w};
#pragma unroll
            for (int kk = 0; kk < 8; ++kk){
                float xv = xs[kk];
#pragma unroll
                for (int ri = 0; ri < 8; ++ri)
                    a[bi*8+ri] = fmaf(xv, wi[ri*8+kk], a[bi*8+ri]);
            }
        }

        // ---- wait for step s-1 of all 128 wgs in this direction
        if (s > 0){
            if (wid == 0){
                for (;;){
                    int v0 = __hip_atomic_load(barf + lane,      __ATOMIC_RELAXED, __HIP_MEMORY_SCOPE_AGENT);
                    int v1 = __hip_atomic_load(barf + 64 + lane, __ATOMIC_RELAXED, __HIP_MEMORY_SCOPE_AGENT);
                    if (__all((v0 >= s) && (v1 >= s))) break;
                    __builtin_amdgcn_s_sleep(1);
                }
            }
            __syncthreads();

            // ---- h-projection from compact layout: lane L reads full lines
            //      (slice 2L, 2L+1) at its batch-group offset; fresh addresses.
            const int tprev = dir ? (T - s) : (s - 1);
            const float* hb = HX + (size_t)(dir*T + tprev)*8192;   // 128*64
#pragma unroll
            for (int bi = 0; bi < 4; ++bi){
                const float* lp = hb + lane*128 + (bg*4 + bi)*4;
                float4 h0 = *(const float4*)lp;          // k = lane*8 .. +3
                float4 h1 = *(const float4*)(lp + 64);   // k = lane*8+4 .. +7
                float hs[8] = {h0.x,h0.y,h0.z,h0.w,h1.x,h1.y,h1.z,h1.w};
#pragma unroll
                for (int kk = 0; kk < 8; ++kk){
                    float hv = hs[kk];
#pragma unroll
                    for (int ri = 0; ri < 8; ++ri)
                        a[bi*8+ri] = fmaf(hv, wh[ri*8+kk], a[bi*8+ri]);
                }
            }
        }

        // ---- reduce-scatter: 32 values over 64 lanes (5 stages + merge)
#pragma unroll
        for (int m = 0; m < 5; ++m){
            const int half = 16 >> m;
            const bool up = (lane >> m) & 1;
#pragma unroll
            for (int j = 0; j < 16; ++j){
                if (j < half){
                    float lo = a[j], hi = a[j+half];
                    float rlo = __shfl_xor(lo, 1<<m, 64);
                    float rhi = __shfl_xor(hi, 1<<m, 64);
                    a[j] = up ? (hi + rhi) : (lo + rlo);
                }
            }
        }
        a[0] += __shfl_xor(a[0], 32, 64);   // cross-half k merge

        if ((lane & 32) == 0) gbuf[gslot] = a[0];
        __syncthreads();

        if (tid < 64){   // wave-uniform branch: wave0 only
            float iv = sigmoidf_(gbuf[      tid] + bI);
            float fv = sigmoidf_(gbuf[ 64 + tid] + bF);
            float gv = tanhf_  (gbuf[128 + tid] + bG);
            float ov = sigmoidf_(gbuf[192 + tid] + bO);
            cst = fv*cst + iv*gv;
            float hv = ov * tanhf_(cst);
            // coalesced sc1 store: 64 contiguous floats per wg (256B burst)
            __hip_atomic_store(&HX[((size_t)(dir*T + tp)*128 + slice)*64 + tid], hv,
                               __ATOMIC_RELAXED, __HIP_MEMORY_SCOPE_AGENT);
        }
        // order: h burst acked at LLC before flag store; no L2 flushes
        asm volatile("s_waitcnt vmcnt(0)" ::: "memory");
        __builtin_amdgcn_sched_barrier(0);
        if (tid == 0)
            __hip_atomic_store(barf + slice, s + 1, __ATOMIC_RELAXED, __HIP_MEMORY_SCOPE_AGENT);
        // no trailing barrier needed: gbuf WAR for step s+1 is ordered by the
        // post-poll __syncthreads (wave0 reaches it only after its gbuf reads).
    }
}

// ---------------------------------------------------------------------------
// SH = relu(enc @ ws1.T + bs1)   M=16384 N=512 K=1024, fp32 64x64x16 tiles
// A-tile from compact HX layout (float4 per (row, 4k) stays contiguous).
// ---------------------------------------------------------------------------
__global__ __launch_bounds__(256, 2)
void seg_gemm(const float* __restrict__ ws_, const float* __restrict__ ws1,
              const float* __restrict__ bs1)
{
    const float* HX = ws_ + OFF_HX;
    float* SH = (float*)(ws_ + OFF_SH);
    __shared__ float As[64][17];
    __shared__ float Bs[64][17];
    const int m0 = blockIdx.x * 64;
    const int n0 = blockIdx.y * 64;
    const int tid = threadIdx.x;
    const int r  = tid >> 2;
    const int kq = (tid & 3) * 4;
    const int ty = tid >> 4, tx = tid & 15;
    const int bI = m0 >> 10;          // tile stays inside one batch
    const int t0 = m0 & 1023;

    float acc[4][4];
#pragma unroll
    for (int i=0;i<4;i++)
#pragma unroll
        for (int j=0;j<4;j++) acc[i][j]=0.0f;

    for (int kb = 0; kb < 1024; kb += 16){
        int kk = kb + kq;                 // multiple of 4
        int dA  = (kk < 512) ? 0 : 1;
        int kkL = kk & 511;
        const float* ap = HX + ((size_t)(dA*T + t0 + r)*128 + (kkL >> 2))*64 + bI*4;
        float4 av = *(const float4*)ap;
        As[r][kq+0]=av.x; As[r][kq+1]=av.y; As[r][kq+2]=av.z; As[r][kq+3]=av.w;
        float4 bv = *(const float4*)(ws1 + (size_t)(n0 + r)*1024 + kk);
        Bs[r][kq+0]=bv.x; Bs[r][kq+1]=bv.y; Bs[r][kq+2]=bv.z; Bs[r][kq+3]=bv.w;
        __syncthreads();
#pragma unroll
        for (int k2 = 0; k2 < 16; ++k2){
            float av_[4], bv_[4];
#pragma unroll
            for (int i=0;i<4;i++) av_[i] = As[ty*4+i][k2];
#pragma unroll
            for (int j=0;j<4;j++) bv_[j] = Bs[tx*4+j][k2];
#pragma unroll
            for (int i=0;i<4;i++)
#pragma unroll
                for (int j=0;j<4;j++) acc[i][j] = fmaf(av_[i], bv_[j], acc[i][j]);
        }
        __syncthreads();
    }
#pragma unroll
    for (int i=0;i<4;i++){
        int m = m0 + ty*4 + i;
#pragma unroll
        for (int j=0;j<4;j++){
            int n = n0 + tx*4 + j;
            SH[(size_t)m*512 + n] = fmaxf(acc[i][j] + bs1[n], 0.0f);
        }
    }
}

// ---------------------------------------------------------------------------
// scores -> sigmoid -> seg_probs (ws copy + d_out)
// ---------------------------------------------------------------------------
__global__ void seg_score(const float* __restrict__ ws_, const float* __restrict__ ws2,
                          const float* __restrict__ bs2, float* __restrict__ dout)
{
    const float* SH = ws_ + OFF_SH;
    float* segp = (float*)(ws_ + OFF_SEGP);
    int row  = blockIdx.x*4 + (threadIdx.x >> 6);
    int lane = threadIdx.x & 63;
    const float* p = SH + (size_t)row*512 + lane*8;
    const float* q = ws2 + lane*8;
    float4 a0=*(const float4*)p, a1=*(const float4*)(p+4);
    float4 b0=*(const float4*)q, b1=*(const float4*)(q+4);
    float ssum = a0.x*b0.x + a0.y*b0.y + a0.z*b0.z + a0.w*b0.w
               + a1.x*b1.x + a1.y*b1.y + a1.z*b1.z + a1.w*b1.w;
#pragma unroll
    for (int m=1;m<64;m<<=1) ssum += __shfl_xor(ssum, m, 64);
    if (lane == 0){
        float z = ssum + bs2[0];
        float pr = 1.0f/(1.0f + __expf(-z));
        segp[row] = pr;
        dout[81920 + row] = pr;
    }
}

// ---------------------------------------------------------------------------
// Per-batch: mask scan (count, first-10 idx), pooled -> gctx
// ---------------------------------------------------------------------------
__global__ void select_gctx(float* __restrict__ ws_, const float* __restrict__ wgm,
                            const float* __restrict__ bgv)
{
    const float* HX = ws_ + OFF_HX;
    const float* segp   = ws_ + OFF_SEGP;
    float* gctx = ws_ + OFF_GCTX;
    int* sel = (int*)(ws_ + OFF_SEL);
    int b = blockIdx.x, tid = threadIdx.x;
    __shared__ unsigned char flag[1024];
    __shared__ float pool[1024];
    for (int j = tid; j < 1024; j += 256){
        flag[j] = segp[b*1024 + j] > 0.5f ? 1 : 0;
        pool[j] = (j < 512) ? HX[hx_idx(0, 1023, b, j)]
                            : HX[hx_idx(1, 0, b, j - 512)];
    }
    __syncthreads();
    if (tid == 0){
        int c = 0;
        int tmp[10];
        for (int j = 0; j < 10; ++j) tmp[j] = 0;
        for (int t = 0; t < 1024; ++t){
            if (flag[t]){ if (c < 10) tmp[c] = t; c++; }
        }
        for (int j = 0; j < 10; ++j) sel[b*12 + j] = tmp[j];
        sel[b*12 + 10] = c;
        sel[b*12 + 11] = 0;
    }
    __syncthreads();
    for (int n = tid; n < 1024; n += 256){
        float acc = bgv[n];
        const float* wr = wgm + (size_t)n*1024;
        for (int k = 0; k < 1024; k += 4){
            acc += wr[k]*pool[k] + wr[k+1]*pool[k+1] + wr[k+2]*pool[k+2] + wr[k+3]*pool[k+3];
        }
        gctx[b*1024 + n] = acc;
    }
}

// ---------------------------------------------------------------------------
// Decoder: one block per (b,slot)
// ---------------------------------------------------------------------------
__global__ void decode(const float* __restrict__ ws_, const float* __restrict__ wd1,
                       const float* __restrict__ bd1, const float* __restrict__ wd2,
                       const float* __restrict__ bd2, float* __restrict__ dout)
{
    const float* HX = ws_ + OFF_HX;
    const float* gctx   = ws_ + OFF_GCTX;
    const int* sel = (const int*)(ws_ + OFF_SEL);
    int blk = blockIdx.x;
    int b = blk / 10, slot = blk % 10;
    int tid = threadIdx.x;
    int count = sel[b*12 + 10];
    int nval = count < 10 ? count : 10;
    bool empty = (count == 0);
    float* outp = dout + (size_t)(b*10 + slot)*512;
    if (slot >= nval && !(empty && slot == 0)){
        for (int n = tid; n < 512; n += 256) outp[n] = 0.0f;
        return;
    }
    __shared__ float row[1024];
    __shared__ float dh[512];
    if (empty){
        for (int j = tid; j < 1024; j += 256) row[j] = gctx[b*1024 + j];
    } else {
        int t = sel[b*12 + slot];
        for (int j = tid; j < 1024; j += 256)
            row[j] = (j < 512) ? HX[hx_idx(0, t, b, j)]
                               : HX[hx_idx(1, t, b, j - 512)];
    }
    __syncthreads();
    for (int d = tid; d < 512; d += 256){
        float acc = bd1[d];
        const float* wr = wd1 + (size_t)d*1024;
        for (int k = 0; k < 1024; ++k) acc += wr[k]*row[k];
        dh[d] = fmaxf(acc, 0.0f);
    }
    __syncthreads();
    for (int n = tid; n < 512; n += 256){
        float acc = bd2[n];
        const float* wr = wd2 + (size_t)n*512;
        for (int k = 0; k < 512; ++k) acc += wr[k]*dh[k];
        outp[n] = acc;
    }
}

extern "C" void kernel_launch(void* const* d_in, const int* in_sizes, int n_in,
                              void* d_out, int out_size, void* d_ws, size_t ws_size,
                              hipStream_t stream)
{
    const int*   instr = (const int*)d_in[0];
    const float* emb   = (const float*)d_in[1];
    const float* wih_f = (const float*)d_in[2];
    const float* whh_f = (const float*)d_in[3];
    const float* bih_f = (const float*)d_in[4];
    const float* bhh_f = (const float*)d_in[5];
    const float* wih_b = (const float*)d_in[6];
    const float* whh_b = (const float*)d_in[7];
    const float* bih_b = (const float*)d_in[8];
    const float* bhh_b = (const float*)d_in[9];
    const float* wg_   = (const float*)d_in[10];
    const float* bg_   = (const float*)d_in[11];
    const float* ws1   = (const float*)d_in[12];
    const float* bs1   = (const float*)d_in[13];
    const float* ws2   = (const float*)d_in[14];
    const float* bs2   = (const float*)d_in[15];
    const float* wd1   = (const float*)d_in[16];
    const float* bd1   = (const float*)d_in[17];
    const float* wd2   = (const float*)d_in[18];
    const float* bd2   = (const float*)d_in[19];
    float* out = (float*)d_out;
    float* ws  = (float*)d_ws;

    // zero the per-wg step flags (captured as a memset node; re-runs every replay)
    hipMemsetAsync(d_ws, 0, 1024, stream);

    hipLaunchKernelGGL(lstm_kernel, dim3(256), dim3(512), 0, stream,
                       instr, emb, wih_f, whh_f, bih_f, bhh_f,
                       wih_b, whh_b, bih_b, bhh_b, ws);
    hipLaunchKernelGGL(seg_gemm, dim3(256, 8), dim3(256), 0, stream, ws, ws1, bs1);
    hipLaunchKernelGGL(seg_score, dim3(4096), dim3(256), 0, stream, ws, ws2, bs2, out);
    hipLaunchKernelGGL(select_gctx, dim3(16), dim3(256), 0, stream, ws, wg_, bg_);
    hipLaunchKernelGGL(decode, dim3(160), dim3(256), 0, stream, ws, wd1, bd1, wd2, bd2, out);
}